// Round 1
// 2265.650 us; speedup vs baseline: 1.0013x; 1.0013x over previous
//
#include <hip/hip_runtime.h>
#include <hip/hip_bf16.h>
#include <math.h>

// Problem constants
#define NLAYERS 6
#define DMODEL  1024
#define NHEADS  16
#define DHEAD   64
#define DMLP    4096
#define PSZ     16
#define HWN     14
#define LTOK    196
#define NKEEP   98
#define NIMG    32
#define SEQ     99              // 1 cls + 98 kept
#define NS      (NIMG * SEQ)    // 3168
#define NP      (NIMG * LTOK)   // 6272
#define PDIM    768             // 16*16*3
#define QS      3072            // fused qkv row stride
#define SPAD    112             // seq padded to 7*16
#define VT_PITCH 136            // Vt row pitch (bf16 elems); 272B = 4 banks offset/row
#define P_PITCH  136            // P row pitch

typedef __attribute__((ext_vector_type(8))) short short8;
typedef __attribute__((ext_vector_type(4))) float f32x4;

// async global->LDS, 16B per lane. LDS dest = wave-uniform base + lane*16.
__device__ __forceinline__ void gload16(const void* g, void* l) {
    __builtin_amdgcn_global_load_lds(
        (const __attribute__((address_space(1))) void*)g,
        (__attribute__((address_space(3))) void*)l, 16, 0, 0);
}

// ---------------------------------------------------------------------------
// Weight convert + transpose: W (K x N) fp32 -> Wt (N x K) bf16, batched on z
// ---------------------------------------------------------------------------
__global__ __launch_bounds__(256) void conv_transpose(
    const float* __restrict__ W, __hip_bfloat16* __restrict__ Wt, int K, int N,
    size_t src_zs, size_t dst_zs)
{
    __shared__ float tile[32][33];
    W += (size_t)blockIdx.z * src_zs;
    Wt += (size_t)blockIdx.z * dst_zs;
    int n0 = blockIdx.x * 32, k0 = blockIdx.y * 32;
    int tx = threadIdx.x & 31, ty = threadIdx.x >> 5;  // 32 x 8
#pragma unroll
    for (int i = 0; i < 4; ++i)
        tile[ty + i * 8][tx] = W[(size_t)(k0 + ty + i * 8) * N + n0 + tx];
    __syncthreads();
#pragma unroll
    for (int i = 0; i < 4; ++i)
        Wt[(size_t)(n0 + ty + i * 8) * K + k0 + tx] = __float2bfloat16(tile[tx][ty + i * 8]);
}

// ---------------------------------------------------------------------------
// Concat q/k/v biases into (NL, 3072)
// ---------------------------------------------------------------------------
__global__ __launch_bounds__(256) void concat_bias(
    const float* __restrict__ bq, const float* __restrict__ bk,
    const float* __restrict__ bv, float* __restrict__ bqkv)
{
    int L = blockIdx.y;
    int i = blockIdx.x * 256 + threadIdx.x;   // 0..3071
    float v;
    if (i < DMODEL)            v = bq[L * DMODEL + i];
    else if (i < 2 * DMODEL)   v = bk[L * DMODEL + i - DMODEL];
    else                       v = bv[L * DMODEL + i - 2 * DMODEL];
    bqkv[(size_t)L * QS + i] = v;
}

// ---------------------------------------------------------------------------
// argsort(noise) per image via rank counting; mask written straight to d_out
// ---------------------------------------------------------------------------
__global__ __launch_bounds__(256) void sort_kernel(
    const float* __restrict__ noise, int* __restrict__ ids_keep, float* __restrict__ mask)
{
    int n = blockIdx.x, tid = threadIdx.x;
    __shared__ float nz[LTOK];
    if (tid < LTOK) nz[tid] = noise[n * LTOK + tid];
    __syncthreads();
    if (tid < LTOK) {
        float val = nz[tid];
        int rank = 0;
        for (int j = 0; j < LTOK; ++j) {
            float vj = nz[j];
            rank += (vj < val) || (vj == val && j < tid);
        }
        mask[n * LTOK + tid] = (rank < NKEEP) ? 0.0f : 1.0f;
        if (rank < NKEEP) ids_keep[n * NKEEP + rank] = tid;
    }
}

// ---------------------------------------------------------------------------
// Patchify: imgs (N,224,224,3) -> Apatch (N*196, 768) bf16
// ---------------------------------------------------------------------------
__global__ __launch_bounds__(256) void patchify(
    const float* __restrict__ imgs, __hip_bfloat16* __restrict__ Ap)
{
    int row = blockIdx.x, tid = threadIdx.x;       // 256 threads = 16x16 pixels
    int n = row / LTOK, l = row % LTOK;
    int hy = l / HWN, hx = l % HWN;
    int py = tid >> 4, px = tid & 15;
    const float* src = imgs + (((size_t)(n * 224 + hy * 16 + py)) * 224 + hx * 16 + px) * 3;
    __hip_bfloat16* dst = Ap + (size_t)row * PDIM + tid * 3;
    dst[0] = __float2bfloat16(src[0]);
    dst[1] = __float2bfloat16(src[1]);
    dst[2] = __float2bfloat16(src[2]);
}

// ---------------------------------------------------------------------------
// Gather kept tokens + prepend cls: x (NS, D) fp32
// ---------------------------------------------------------------------------
__global__ __launch_bounds__(256) void gather_cls(
    const float* __restrict__ x0, const float* __restrict__ cls,
    const int* __restrict__ ids_keep, float* __restrict__ x)
{
    int row = blockIdx.x, tid = threadIdx.x;
    int n = row / SEQ, s = row % SEQ;
    const float* src = (s == 0) ? cls
        : x0 + ((size_t)n * LTOK + ids_keep[n * NKEEP + (s - 1)]) * DMODEL;
    reinterpret_cast<float4*>(x + (size_t)row * DMODEL)[tid] =
        reinterpret_cast<const float4*>(src)[tid];
}

// ---------------------------------------------------------------------------
// LayerNorm: one block per row (D=1024, 256 thr x 4). OUTMODE 0: fp32, 1: bf16
// ---------------------------------------------------------------------------
template <int OUTMODE>
__global__ __launch_bounds__(256) void ln_kernel(
    const float* __restrict__ x, const float* __restrict__ s, const float* __restrict__ b,
    float* __restrict__ of, __hip_bfloat16* __restrict__ ob)
{
    int row = blockIdx.x, tid = threadIdx.x;
    int lane = tid & 63, wid = tid >> 6;
    float4 t = reinterpret_cast<const float4*>(x + (size_t)row * DMODEL)[tid];
    float sum = t.x + t.y + t.z + t.w;
    float sq  = t.x * t.x + t.y * t.y + t.z * t.z + t.w * t.w;
#pragma unroll
    for (int m = 1; m < 64; m <<= 1) { sum += __shfl_xor(sum, m); sq += __shfl_xor(sq, m); }
    __shared__ float sm[8];
    if (lane == 0) { sm[wid] = sum; sm[4 + wid] = sq; }
    __syncthreads();
    sum = sm[0] + sm[1] + sm[2] + sm[3];
    sq  = sm[4] + sm[5] + sm[6] + sm[7];
    float mean = sum * (1.0f / DMODEL);
    float var  = sq * (1.0f / DMODEL) - mean * mean;
    float rstd = rsqrtf(var + 1e-6f);
    float4 sv = reinterpret_cast<const float4*>(s)[tid];
    float4 bv = reinterpret_cast<const float4*>(b)[tid];
    float o0 = (t.x - mean) * rstd * sv.x + bv.x;
    float o1 = (t.y - mean) * rstd * sv.y + bv.y;
    float o2 = (t.z - mean) * rstd * sv.z + bv.z;
    float o3 = (t.w - mean) * rstd * sv.w + bv.w;
    if (OUTMODE == 0) {
        reinterpret_cast<float4*>(of + (size_t)row * DMODEL)[tid] = make_float4(o0, o1, o2, o3);
    } else {
        __hip_bfloat16* p = ob + (size_t)row * DMODEL + tid * 4;
        p[0] = __float2bfloat16(o0); p[1] = __float2bfloat16(o1);
        p[2] = __float2bfloat16(o2); p[3] = __float2bfloat16(o3);
    }
}

// ---------------------------------------------------------------------------
// MFMA bf16 GEMM, double-buffered LDS (T3 2-phase): C(MxN) = A @ Wt^T + bias.
// Prefetch of K-step t+1 is issued BEFORE compute of step t; the single
// __syncthreads() per step (vmcnt+lgkm drain) is the pipeline sync point.
// gridDim.z = split-K factor (MODE 1 only; partial sums via atomicAdd).
// ---------------------------------------------------------------------------
template <int MODE>
__global__ __launch_bounds__(256) void gemm_mfma(
    const __hip_bfloat16* __restrict__ A, const __hip_bfloat16* __restrict__ Wt,
    const float* __restrict__ bias, const float* __restrict__ pos,
    float* __restrict__ Cf, __hip_bfloat16* __restrict__ Cb,
    int M, int N, int K)
{
    __shared__ __hip_bfloat16 As[2][128 * 32];   // 2 x 8 KB; slot = kc ^ ((row>>1)&3)
    __shared__ __hip_bfloat16 Bs[2][128 * 32];   // 2 x 8 KB

    int tid = threadIdx.x;
    int lane = tid & 63, wid = tid >> 6;
    int quad = lane >> 4, l16 = lane & 15;
    int wm = wid & 1, wn = wid >> 1;
    int bm = blockIdx.x * 128, bn = blockIdx.y * 128;
    int Kc = K / gridDim.z;             // per-slice K chunk (multiple of 64)
    int koff = blockIdx.z * Kc;

    int rowA0 = tid >> 2,        rowA1 = (tid + 256) >> 2;
    int kcA0 = (tid & 3) ^ ((tid >> 3) & 3);
    int kcA1 = (tid & 3) ^ (((tid + 256) >> 3) & 3);
    int arow0 = bm + rowA0; if (arow0 >= M) arow0 = M - 1;
    int arow1 = bm + rowA1; if (arow1 >= M) arow1 = M - 1;
    const short* Ag0 = reinterpret_cast<const short*>(A) + (size_t)arow0 * K + koff + kcA0 * 8;
    const short* Ag1 = reinterpret_cast<const short*>(A) + (size_t)arow1 * K + koff + kcA1 * 8;
    const short* Bg0 = reinterpret_cast<const short*>(Wt) + (size_t)(bn + rowA0) * K + koff + kcA0 * 8;
    const short* Bg1 = reinterpret_cast<const short*>(Wt) + (size_t)(bn + rowA1) * K + koff + kcA1 * 8;

    int aOff[4], bOff[4];
#pragma unroll
    for (int t = 0; t < 4; ++t) {
        int row = wm * 64 + t * 16 + l16;
        aOff[t] = row * 64 + (quad ^ ((row >> 1) & 3)) * 16;
        int col = wn * 64 + t * 16 + l16;
        bOff[t] = col * 64 + (quad ^ ((col >> 1) & 3)) * 16;
    }

    f32x4 acc[4][4];
#pragma unroll
    for (int t = 0; t < 4; ++t)
#pragma unroll
        for (int u = 0; u < 4; ++u) { f32x4 z = {0.f, 0.f, 0.f, 0.f}; acc[t][u] = z; }

    auto stage = [&](int buf, int k0) {
        char* ad = (char*)As[buf];
        char* bd = (char*)Bs[buf];
        gload16(Ag0 + k0, ad + tid * 16);
        gload16(Ag1 + k0, ad + (tid + 256) * 16);
        gload16(Bg0 + k0, bd + tid * 16);
        gload16(Bg1 + k0, bd + (tid + 256) * 16);
    };
    auto compute = [&](int buf) {
        const char* ab = (const char*)As[buf];
        const char* bb = (const char*)Bs[buf];
        short8 a[4], b[4];
#pragma unroll
        for (int t = 0; t < 4; ++t) a[t] = *reinterpret_cast<const short8*>(ab + aOff[t]);
#pragma unroll
        for (int u = 0; u < 4; ++u) b[u] = *reinterpret_cast<const short8*>(bb + bOff[u]);
#pragma unroll
        for (int t = 0; t < 4; ++t)
#pragma unroll
            for (int u = 0; u < 4; ++u)
                acc[t][u] = __builtin_amdgcn_mfma_f32_16x16x32_bf16(a[t], b[u], acc[t][u], 0, 0, 0);
    };

    // prologue: fill buf0
    stage(0, 0);
    __syncthreads();
    // main loop, unrolled x2 so buffer indices are compile-time (Kc % 64 == 0)
    for (int k0 = 0; k0 < Kc; k0 += 64) {
        stage(1, k0 + 32);                       // prefetch t+1, overlaps compute(t)
        compute(0);
        __syncthreads();                          // drains vmcnt (buf1 ready) + lgkm
        if (k0 + 64 < Kc) stage(0, k0 + 64);      // prefetch t+2, overlaps compute(t+1)
        compute(1);
        __syncthreads();
    }

    // C/D layout: col = lane&15, row = quad*4 + reg   [verified m89]
    bool addb = (bias != nullptr) && (blockIdx.z == 0);
#pragma unroll
    for (int t = 0; t < 4; ++t) {
#pragma unroll
        for (int u = 0; u < 4; ++u) {
            int col = bn + wn * 64 + u * 16 + l16;
            float bcol = addb ? bias[col] : 0.0f;
#pragma unroll
            for (int i = 0; i < 4; ++i) {
                int row = bm + wm * 64 + t * 16 + quad * 4 + i;
                if (row >= M) continue;
                float val = acc[t][u][i] + bcol;
                size_t idx = (size_t)row * N + col;
                if (MODE == 0) {
                    if (pos) val += pos[(size_t)(row % LTOK) * N + col];
                    Cf[idx] = val;
                } else if (MODE == 1) {
                    atomicAdd(&Cf[idx], val);     // split-K partial accumulate
                } else if (MODE == 2) {
                    float u3 = val * val * val;
                    float g = 0.5f * val *
                        (1.0f + tanhf(0.7978845608028654f * (val + 0.044715f * u3)));
                    Cb[idx] = __float2bfloat16(g);
                } else {
                    Cb[idx] = __float2bfloat16(val);
                }
            }
        }
    }
}

// ---------------------------------------------------------------------------
// MFMA attention: one block per (n, h); 4 waves, each owns Q-tiles qt, qt+4.
// S=99 padded to 112 (7 key tiles of 16). q/k fragments loaded directly from
// global (16B contiguous); V transposed into LDS once; P via wave-private LDS.
// ---------------------------------------------------------------------------
__global__ __launch_bounds__(256) void attn_mfma(
    const __hip_bfloat16* __restrict__ qkv, __hip_bfloat16* __restrict__ o)
{
    int n = blockIdx.x >> 4, h = blockIdx.x & 15;
    int tid = threadIdx.x, lane = tid & 63, wid = tid >> 6;
    int quad = lane >> 4, l16 = lane & 15;

    __shared__ __hip_bfloat16 Vt[DHEAD * VT_PITCH];      // [d][key] 17408 B
    __shared__ __hip_bfloat16 Ps[4][16 * P_PITCH];       // wave-private P, 17408 B

    // zero Vt (pad keys >= 99 must be 0) and Ps (pad cols 112.. must be 0)
    {
        int4 zz = make_int4(0, 0, 0, 0);
        int4* v4 = (int4*)Vt;
        int4* p4 = (int4*)Ps;
        for (int i = tid; i < (DHEAD * VT_PITCH) / 8; i += 256) v4[i] = zz;
        for (int i = tid; i < (4 * 16 * P_PITCH) / 8; i += 256) p4[i] = zz;
    }
    __syncthreads();
    // stage V transposed: Vt[d][s] = v[s][d]
    for (int idx = tid; idx < SEQ * DHEAD; idx += 256) {
        int s = idx >> 6, d = idx & 63;
        Vt[d * VT_PITCH + s] = qkv[((size_t)(n * SEQ + s)) * QS + 2 * DMODEL + h * DHEAD + d];
    }
    __syncthreads();

    const short* qbase = reinterpret_cast<const short*>(qkv) + (size_t)n * SEQ * QS + h * DHEAD;
    const short* kbase = qbase + DMODEL;
    const float scale = 0.125f;  // 1/sqrt(64)

    for (int qt = wid; qt < 7; qt += 4) {
        int q0 = qt * 16;
        // A-fragments of Q: lane m=l16 -> row q0+l16, k = c*32 + quad*8
        int qrow = q0 + l16; if (qrow >= SEQ) qrow = SEQ - 1;
        const short* qp = qbase + (size_t)qrow * QS + quad * 8;
        short8 aq0 = *reinterpret_cast<const short8*>(qp);
        short8 aq1 = *reinterpret_cast<const short8*>(qp + 32);

        // QK^T: scores sc[u] for key tile u (C-layout: row=quad*4+i, col=l16)
        f32x4 sc[7];
#pragma unroll
        for (int u = 0; u < 7; ++u) {
            int krow = u * 16 + l16; if (krow >= SEQ) krow = SEQ - 1;
            const short* kp = kbase + (size_t)krow * QS + quad * 8;
            short8 kb0 = *reinterpret_cast<const short8*>(kp);
            short8 kb1 = *reinterpret_cast<const short8*>(kp + 32);
            f32x4 s = {0.f, 0.f, 0.f, 0.f};
            s = __builtin_amdgcn_mfma_f32_16x16x32_bf16(aq0, kb0, s, 0, 0, 0);
            s = __builtin_amdgcn_mfma_f32_16x16x32_bf16(aq1, kb1, s, 0, 0, 0);
            sc[u] = s;
        }
        // scale + mask keys >= 99 (only tile u=6: keys 96..111 -> l16 >= 3)
#pragma unroll
        for (int u = 0; u < 7; ++u)
#pragma unroll
            for (int i = 0; i < 4; ++i)
                sc[u][i] *= scale;
        if (l16 >= 3) {
#pragma unroll
            for (int i = 0; i < 4; ++i) sc[6][i] = -1e30f;
        }
        // row softmax (row = quad*4+i spans 16 lanes l16 x 7 tiles)
#pragma unroll
        for (int i = 0; i < 4; ++i) {
            float m = sc[0][i];
#pragma unroll
            for (int u = 1; u < 7; ++u) m = fmaxf(m, sc[u][i]);
            m = fmaxf(m, __shfl_xor(m, 1));
            m = fmaxf(m, __shfl_xor(m, 2));
            m = fmaxf(m, __shfl_xor(m, 4));
            m = fmaxf(m, __shfl_xor(m, 8));
            float sum = 0.f;
#pragma unroll
            for (int u = 0; u < 7; ++u) {
                float e = __expf(sc[u][i] - m);
                sc[u][i] = e;
                sum += e;
            }
            sum += __shfl_xor(sum, 1);
            sum += __shfl_xor(sum, 2);
            sum += __shfl_xor(sum, 4);
            sum += __shfl_xor(sum, 8);
            float inv = 1.0f / sum;
            // write P row (C-layout -> LDS), cols 112..135 stay zero
            __hip_bfloat16* pr = &Ps[wid][(quad * 4 + i) * P_PITCH];
#pragma unroll
            for (int u = 0; u < 7; ++u)
                pr[u * 16 + l16] = __float2bfloat16(sc[u][i] * inv);
        }
        // PV: A = P (A-layout: lane m=l16 -> row l16, k = kc*32+quad*8)
        short8 ap[4];
#pragma unroll
        for (int kc = 0; kc < 4; ++kc)
            ap[kc] = *reinterpret_cast<const short8*>(&Ps[wid][l16 * P_PITCH + kc * 32 + quad * 8]);
        f32x4 oacc[4];
#pragma unroll
        for (int dt = 0; dt < 4; ++dt) { f32x4 z = {0.f, 0.f, 0.f, 0.f}; oacc[dt] = z; }
#pragma unroll
        for (int kc = 0; kc < 4; ++kc) {
#pragma unroll
            for (int dt = 0; dt < 4; ++dt) {
                short8 vb = *reinterpret_cast<const short8*>(
                    &Vt[(dt * 16 + l16) * VT_PITCH + kc * 32 + quad * 8]);
                oacc[dt] = __builtin_amdgcn_mfma_f32_16x16x32_bf16(ap[kc], vb, oacc[dt], 0, 0, 0);
            }
        }
        // store O (C-layout): row q0+quad*4+i, col = h*64 + dt*16+l16
#pragma unroll
        for (int dt = 0; dt < 4; ++dt) {
#pragma unroll
            for (int i = 0; i < 4; ++i) {
                int row = q0 + quad * 4 + i;
                if (row < SEQ)
                    o[((size_t)(n * SEQ + row)) * DMODEL + h * DHEAD + dt * 16 + l16] =
                        __float2bfloat16(oacc[dt][i]);
            }
        }
    }
}

// ---------------------------------------------------------------------------
extern "C" void kernel_launch(void* const* d_in, const int* in_sizes, int n_in,
                              void* d_out, int out_size, void* d_ws, size_t ws_size,
                              hipStream_t stream)
{
    (void)in_sizes; (void)n_in; (void)out_size; (void)ws_size;
    const float* imgs    = (const float*)d_in[0];
    const float* noise   = (const float*)d_in[1];
    const float* patch_w = (const float*)d_in[2];
    const float* patch_b = (const float*)d_in[3];
    const float* pos_emb = (const float*)d_in[4];
    const float* cls     = (const float*)d_in[5];
    const float* ln1_s   = (const float*)d_in[6];
    const float* ln1_b   = (const float*)d_in[7];
    const float* wq      = (const float*)d_in[8];
    const float* bq      = (const float*)d_in[9];
    const float* wk      = (const float*)d_in[10];
    const float* bk      = (const float*)d_in[11];
    const float* wv      = (const float*)d_in[12];
    const float* bv      = (const float*)d_in[13];
    const float* wo      = (const float*)d_in[14];
    const float* bo      = (const float*)d_in[15];
    const float* ln2_s   = (const float*)d_in[16];
    const float* ln2_b   = (const float*)d_in[17];
    const float* w1      = (const float*)d_in[18];
    const float* b1      = (const float*)d_in[19];
    const float* w2      = (const float*)d_in[20];
    const float* b2      = (const float*)d_in[21];
    const float* lnf_s   = (const float*)d_in[22];
    const float* lnf_b   = (const float*)d_in[23];

    float* out_x    = (float*)d_out;
    float* out_mask = out_x + (size_t)NS * DMODEL;

    // ---- workspace carve-up ----
    char* p = (char*)d_ws;
    auto alloc = [&](size_t bytes) {
        char* r = p; p += (bytes + 255) & ~(size_t)255; return r;
    };
    __hip_bfloat16* patch_wt = (__hip_bfloat16*)alloc((size_t)DMODEL * PDIM * 2);
    __hip_bfloat16* wqkvt    = (__hip_bfloat16*)alloc((size_t)NLAYERS * QS * DMODEL * 2);
    __hip_bfloat16* wot = (__hip_bfloat16*)alloc((size_t)NLAYERS * DMODEL * DMODEL * 2);
    __hip_bfloat16* w1t = (__hip_bfloat16*)alloc((size_t)NLAYERS * DMODEL * DMLP * 2);
    __hip_bfloat16* w2t = (__hip_bfloat16*)alloc((size_t)NLAYERS * DMODEL * DMLP * 2);
    float* bqkv     = (float*)alloc((size_t)NLAYERS * QS * 4);
    int*   ids_keep = (int*)alloc((size_t)NIMG * NKEEP * 4);
    float* x        = (float*)alloc((size_t)NS * DMODEL * 4);
    // scratch region: layer buffers, aliased with pre-layer Apatch/x0
    char* scratch = p;
    __hip_bfloat16* ybf  = (__hip_bfloat16*)alloc((size_t)NS * DMODEL * 2);
    __hip_bfloat16* qkv  = (__hip_bfloat16*)alloc((size_t)NS * QS * 2);
    __hip_bfloat16* obf  = (__hip_bfloat16*)alloc((size_t)NS * DMODEL * 2);
    __hip_bfloat16* h1bf = (__hip_bfloat16*)alloc((size_t)NS * DMLP * 2);
    // aliases (dead once gather_cls has run):
    __hip_bfloat16* Apatch = (__hip_bfloat16*)scratch;                       // NP*PDIM bf16
    float* x0 = (float*)(scratch + (((size_t)NP * PDIM * 2 + 255) & ~(size_t)255)); // NP*D f32

    const size_t DD = (size_t)DMODEL * DMODEL;
    const size_t DM = (size_t)DMODEL * DMLP;

    // ---- weight conversion (every call; ws is re-poisoned) ----
    conv_transpose<<<dim3(DMODEL / 32, PDIM / 32, 1), 256, 0, stream>>>(
        patch_w, patch_wt, PDIM, DMODEL, PDIM * DMODEL, PDIM * DMODEL);
    conv_transpose<<<dim3(DMODEL / 32, DMODEL / 32, NLAYERS), 256, 0, stream>>>(
        wq, wqkvt, DMODEL, DMODEL, DD, (size_t)QS * DMODEL);
    conv_transpose<<<dim3(DMODEL / 32, DMODEL / 32, NLAYERS), 256, 0, stream>>>(
        wk, wqkvt + DD, DMODEL, DMODEL, DD, (size_t)QS * DMODEL);
    conv_transpose<<<dim3(DMODEL / 32, DMODEL / 32, NLAYERS), 256, 0, stream>>>(
        wv, wqkvt + 2 * DD, DMODEL, DMODEL, DD, (size_t)QS * DMODEL);
    conv_transpose<<<dim3(DMODEL / 32, DMODEL / 32, NLAYERS), 256, 0, stream>>>(
        wo, wot, DMODEL, DMODEL, DD, DD);
    conv_transpose<<<dim3(DMLP / 32, DMODEL / 32, NLAYERS), 256, 0, stream>>>(
        w1, w1t, DMODEL, DMLP, DM, DM);
    conv_transpose<<<dim3(DMODEL / 32, DMLP / 32, NLAYERS), 256, 0, stream>>>(
        w2, w2t, DMLP, DMODEL, DM, DM);
    concat_bias<<<dim3(QS / 256, NLAYERS), 256, 0, stream>>>(bq, bk, bv, bqkv);

    // ---- masking / patch embed ----
    sort_kernel<<<NIMG, 256, 0, stream>>>(noise, ids_keep, out_mask);
    patchify<<<NP, 256, 0, stream>>>(imgs, Apatch);
    gemm_mfma<0><<<dim3(NP / 128, DMODEL / 128), 256, 0, stream>>>(
        Apatch, patch_wt, patch_b, pos_emb, x0, nullptr, NP, DMODEL, PDIM);
    gather_cls<<<NS, 256, 0, stream>>>(x0, cls, ids_keep, x);

    // ---- transformer layers ----
    dim3 gQKV((NS + 127) / 128, QS / 128);
    dim3 gD((NS + 127) / 128, DMODEL / 128);
    dim3 gM((NS + 127) / 128, DMLP / 128);
    dim3 gWo((NS + 127) / 128, DMODEL / 128, 2);   // split-K=2 (K=1024 -> 512/slice)
    dim3 gW2((NS + 127) / 128, DMODEL / 128, 4);   // split-K=4 (K=4096 -> 1024/slice)
    for (int L = 0; L < NLAYERS; ++L) {
        size_t wDD = (size_t)L * DD;
        size_t wDM = (size_t)L * DM;
        ln_kernel<1><<<NS, 256, 0, stream>>>(x, ln1_s + L * DMODEL, ln1_b + L * DMODEL, nullptr, ybf);
        gemm_mfma<3><<<gQKV, 256, 0, stream>>>(ybf, wqkvt + (size_t)L * QS * DMODEL,
                                               bqkv + (size_t)L * QS, nullptr, nullptr, qkv,
                                               NS, QS, DMODEL);
        attn_mfma<<<NIMG * NHEADS, 256, 0, stream>>>(qkv, obf);
        gemm_mfma<1><<<gWo, 256, 0, stream>>>(obf, wot + wDD, bo + L * DMODEL, nullptr, x, nullptr, NS, DMODEL, DMODEL);
        ln_kernel<1><<<NS, 256, 0, stream>>>(x, ln2_s + L * DMODEL, ln2_b + L * DMODEL, nullptr, ybf);
        gemm_mfma<2><<<gM, 256, 0, stream>>>(ybf, w1t + wDM, b1 + L * DMLP, nullptr, nullptr, h1bf, NS, DMLP, DMODEL);
        gemm_mfma<1><<<gW2, 256, 0, stream>>>(h1bf, w2t + wDM, b2 + L * DMODEL, nullptr, x, nullptr, NS, DMODEL, DMLP);
    }

    // ---- final LN -> output ----
    ln_kernel<0><<<NS, 256, 0, stream>>>(x, lnf_s, lnf_b, out_x, nullptr);
}

// Round 3
// 2037.374 us; speedup vs baseline: 1.1135x; 1.1120x over previous
//
#include <hip/hip_runtime.h>
#include <hip/hip_bf16.h>
#include <math.h>

// Problem constants
#define NLAYERS 6
#define DMODEL  1024
#define NHEADS  16
#define DHEAD   64
#define DMLP    4096
#define PSZ     16
#define HWN     14
#define LTOK    196
#define NKEEP   98
#define NIMG    32
#define SEQ     99              // 1 cls + 98 kept
#define NS      (NIMG * SEQ)    // 3168
#define NP      (NIMG * LTOK)   // 6272
#define PDIM    768             // 16*16*3
#define QS      3072            // fused qkv row stride
#define SPAD    112             // seq padded to 7*16
#define VT_PITCH 136            // Vt row pitch (bf16 elems); 272B = 4 banks offset/row
#define P_PITCH  136            // P row pitch

typedef __attribute__((ext_vector_type(8))) short short8;
typedef __attribute__((ext_vector_type(4))) float f32x4;

// async global->LDS, 16B per lane. LDS dest = wave-uniform base + lane*16.
__device__ __forceinline__ void gload16(const void* g, void* l) {
    __builtin_amdgcn_global_load_lds(
        (const __attribute__((address_space(1))) void*)g,
        (__attribute__((address_space(3))) void*)l, 16, 0, 0);
}

// ---------------------------------------------------------------------------
// Weight convert + transpose: W (K x N) fp32 -> Wt (N x K) bf16, batched on z
// ---------------------------------------------------------------------------
__global__ __launch_bounds__(256) void conv_transpose(
    const float* __restrict__ W, __hip_bfloat16* __restrict__ Wt, int K, int N,
    size_t src_zs, size_t dst_zs)
{
    __shared__ float tile[32][33];
    W += (size_t)blockIdx.z * src_zs;
    Wt += (size_t)blockIdx.z * dst_zs;
    int n0 = blockIdx.x * 32, k0 = blockIdx.y * 32;
    int tx = threadIdx.x & 31, ty = threadIdx.x >> 5;  // 32 x 8
#pragma unroll
    for (int i = 0; i < 4; ++i)
        tile[ty + i * 8][tx] = W[(size_t)(k0 + ty + i * 8) * N + n0 + tx];
    __syncthreads();
#pragma unroll
    for (int i = 0; i < 4; ++i)
        Wt[(size_t)(n0 + ty + i * 8) * K + k0 + tx] = __float2bfloat16(tile[tx][ty + i * 8]);
}

// ---------------------------------------------------------------------------
// Concat q/k/v biases into (NL, 3072)
// ---------------------------------------------------------------------------
__global__ __launch_bounds__(256) void concat_bias(
    const float* __restrict__ bq, const float* __restrict__ bk,
    const float* __restrict__ bv, float* __restrict__ bqkv)
{
    int L = blockIdx.y;
    int i = blockIdx.x * 256 + threadIdx.x;   // 0..3071
    float v;
    if (i < DMODEL)            v = bq[L * DMODEL + i];
    else if (i < 2 * DMODEL)   v = bk[L * DMODEL + i - DMODEL];
    else                       v = bv[L * DMODEL + i - 2 * DMODEL];
    bqkv[(size_t)L * QS + i] = v;
}

// ---------------------------------------------------------------------------
// argsort(noise) per image via rank counting; mask written straight to d_out
// ---------------------------------------------------------------------------
__global__ __launch_bounds__(256) void sort_kernel(
    const float* __restrict__ noise, int* __restrict__ ids_keep, float* __restrict__ mask)
{
    int n = blockIdx.x, tid = threadIdx.x;
    __shared__ float nz[LTOK];
    if (tid < LTOK) nz[tid] = noise[n * LTOK + tid];
    __syncthreads();
    if (tid < LTOK) {
        float val = nz[tid];
        int rank = 0;
        for (int j = 0; j < LTOK; ++j) {
            float vj = nz[j];
            rank += (vj < val) || (vj == val && j < tid);
        }
        mask[n * LTOK + tid] = (rank < NKEEP) ? 0.0f : 1.0f;
        if (rank < NKEEP) ids_keep[n * NKEEP + rank] = tid;
    }
}

// ---------------------------------------------------------------------------
// Patchify: imgs (N,224,224,3) -> Apatch (N*196, 768) bf16
// ---------------------------------------------------------------------------
__global__ __launch_bounds__(256) void patchify(
    const float* __restrict__ imgs, __hip_bfloat16* __restrict__ Ap)
{
    int row = blockIdx.x, tid = threadIdx.x;       // 256 threads = 16x16 pixels
    int n = row / LTOK, l = row % LTOK;
    int hy = l / HWN, hx = l % HWN;
    int py = tid >> 4, px = tid & 15;
    const float* src = imgs + (((size_t)(n * 224 + hy * 16 + py)) * 224 + hx * 16 + px) * 3;
    __hip_bfloat16* dst = Ap + (size_t)row * PDIM + tid * 3;
    dst[0] = __float2bfloat16(src[0]);
    dst[1] = __float2bfloat16(src[1]);
    dst[2] = __float2bfloat16(src[2]);
}

// ---------------------------------------------------------------------------
// Gather kept tokens + prepend cls: x (NS, D) fp32
// ---------------------------------------------------------------------------
__global__ __launch_bounds__(256) void gather_cls(
    const float* __restrict__ x0, const float* __restrict__ cls,
    const int* __restrict__ ids_keep, float* __restrict__ x)
{
    int row = blockIdx.x, tid = threadIdx.x;
    int n = row / SEQ, s = row % SEQ;
    const float* src = (s == 0) ? cls
        : x0 + ((size_t)n * LTOK + ids_keep[n * NKEEP + (s - 1)]) * DMODEL;
    reinterpret_cast<float4*>(x + (size_t)row * DMODEL)[tid] =
        reinterpret_cast<const float4*>(src)[tid];
}

// ---------------------------------------------------------------------------
// LayerNorm + optional split-K partial reduce folded in:
// NPART==2: x_new = x + part[0] + part[1] + rb  (written back to xw), LN(x_new)
// OUTMODE 0: fp32 out, 1: bf16 out
// ---------------------------------------------------------------------------
template <int OUTMODE, int NPART>
__global__ __launch_bounds__(256) void ln_kernel(
    const float* __restrict__ x, float* __restrict__ xw,
    const float* __restrict__ part, const float* __restrict__ rb,
    const float* __restrict__ s, const float* __restrict__ b,
    float* __restrict__ of, __hip_bfloat16* __restrict__ ob)
{
    int row = blockIdx.x, tid = threadIdx.x;
    int lane = tid & 63, wid = tid >> 6;
    float4 t = reinterpret_cast<const float4*>(x + (size_t)row * DMODEL)[tid];
    if (NPART == 2) {
        float4 a0 = reinterpret_cast<const float4*>(part + (size_t)row * DMODEL)[tid];
        float4 a1 = reinterpret_cast<const float4*>(part + (size_t)(NS + row) * DMODEL)[tid];
        float4 rv = reinterpret_cast<const float4*>(rb)[tid];
        t.x += a0.x + a1.x + rv.x;
        t.y += a0.y + a1.y + rv.y;
        t.z += a0.z + a1.z + rv.z;
        t.w += a0.w + a1.w + rv.w;
        reinterpret_cast<float4*>(xw + (size_t)row * DMODEL)[tid] = t;
    }
    float sum = t.x + t.y + t.z + t.w;
    float sq  = t.x * t.x + t.y * t.y + t.z * t.z + t.w * t.w;
#pragma unroll
    for (int m = 1; m < 64; m <<= 1) { sum += __shfl_xor(sum, m); sq += __shfl_xor(sq, m); }
    __shared__ float sm[8];
    if (lane == 0) { sm[wid] = sum; sm[4 + wid] = sq; }
    __syncthreads();
    sum = sm[0] + sm[1] + sm[2] + sm[3];
    sq  = sm[4] + sm[5] + sm[6] + sm[7];
    float mean = sum * (1.0f / DMODEL);
    float var  = sq * (1.0f / DMODEL) - mean * mean;
    float rstd = rsqrtf(var + 1e-6f);
    float4 sv = reinterpret_cast<const float4*>(s)[tid];
    float4 bv = reinterpret_cast<const float4*>(b)[tid];
    float o0 = (t.x - mean) * rstd * sv.x + bv.x;
    float o1 = (t.y - mean) * rstd * sv.y + bv.y;
    float o2 = (t.z - mean) * rstd * sv.z + bv.z;
    float o3 = (t.w - mean) * rstd * sv.w + bv.w;
    if (OUTMODE == 0) {
        reinterpret_cast<float4*>(of + (size_t)row * DMODEL)[tid] = make_float4(o0, o1, o2, o3);
    } else {
        __hip_bfloat16* p = ob + (size_t)row * DMODEL + tid * 4;
        p[0] = __float2bfloat16(o0); p[1] = __float2bfloat16(o1);
        p[2] = __float2bfloat16(o2); p[3] = __float2bfloat16(o3);
    }
}

// ---------------------------------------------------------------------------
// MFMA bf16 GEMM, 3-buffer pipeline with counted vmcnt (T3+T4) + XCD swizzle.
// Per K-step: vmcnt(4) -> s_barrier -> sched_barrier(0) -> stage(t+2) ->
// compute(t). Buf b is overwritten only after the barrier proving all waves
// finished compute(b) (period-3 reuse). sched_barrier(0) pins compute's
// ds_reads below the s_barrier (rule #18). vmcnt never 0 in steady state.
// MODE: 0 fp32+pos, 1 fp32 accumulate (+=), 2 gelu->bf16, 3 bf16+bias,
//       4 fp32 partial slice (split-K, reduce folded into next LN)
// ---------------------------------------------------------------------------
template <int MODE>
__global__ __launch_bounds__(256) void gemm_mfma(
    const __hip_bfloat16* __restrict__ A, const __hip_bfloat16* __restrict__ Wt,
    const float* __restrict__ bias, const float* __restrict__ pos,
    float* __restrict__ Cf, __hip_bfloat16* __restrict__ Cb,
    int M, int N, int K)
{
    __shared__ __hip_bfloat16 As[3][128 * 32];   // 3 x 8 KB; slot = kc ^ ((row>>1)&3)
    __shared__ __hip_bfloat16 Bs[3][128 * 32];   // 3 x 8 KB

    // XCD-aware bijective swizzle (m204): each XCD gets a contiguous wg-range;
    // x (M-tile) fastest => same-XCD blocks share the B (weight) panel in L2.
    int nwg = gridDim.x * gridDim.y * gridDim.z;
    int orig = (blockIdx.z * gridDim.y + blockIdx.y) * gridDim.x + blockIdx.x;
    int q = nwg >> 3, r = nwg & 7, xcd = orig & 7, lin = orig >> 3;
    int wg = (xcd < r ? xcd * (q + 1) : r * (q + 1) + (xcd - r) * q) + lin;
    int bx = wg % gridDim.x;
    int tmp = wg / gridDim.x;
    int by = tmp % gridDim.y;
    int bz = tmp / gridDim.y;

    int tid = threadIdx.x;
    int lane = tid & 63, wid = tid >> 6;
    int quad = lane >> 4, l16 = lane & 15;
    int wm = wid & 1, wn = wid >> 1;
    int bm = bx * 128, bn = by * 128;
    int Kc = K / gridDim.z;             // per-slice K chunk (multiple of 64)
    int koff = bz * Kc;

    int rowA0 = tid >> 2,        rowA1 = (tid + 256) >> 2;
    int kcA0 = (tid & 3) ^ ((tid >> 3) & 3);
    int kcA1 = (tid & 3) ^ (((tid + 256) >> 3) & 3);
    int arow0 = bm + rowA0; if (arow0 >= M) arow0 = M - 1;
    int arow1 = bm + rowA1; if (arow1 >= M) arow1 = M - 1;
    const short* Ag0 = reinterpret_cast<const short*>(A) + (size_t)arow0 * K + koff + kcA0 * 8;
    const short* Ag1 = reinterpret_cast<const short*>(A) + (size_t)arow1 * K + koff + kcA1 * 8;
    const short* Bg0 = reinterpret_cast<const short*>(Wt) + (size_t)(bn + rowA0) * K + koff + kcA0 * 8;
    const short* Bg1 = reinterpret_cast<const short*>(Wt) + (size_t)(bn + rowA1) * K + koff + kcA1 * 8;

    int aOff[4], bOff[4];
#pragma unroll
    for (int t = 0; t < 4; ++t) {
        int row = wm * 64 + t * 16 + l16;
        aOff[t] = row * 64 + (quad ^ ((row >> 1) & 3)) * 16;
        int col = wn * 64 + t * 16 + l16;
        bOff[t] = col * 64 + (quad ^ ((col >> 1) & 3)) * 16;
    }

    f32x4 acc[4][4];
#pragma unroll
    for (int t = 0; t < 4; ++t)
#pragma unroll
        for (int u = 0; u < 4; ++u) { f32x4 z = {0.f, 0.f, 0.f, 0.f}; acc[t][u] = z; }

    auto stage = [&](int buf, int k0) {
        char* ad = (char*)As[buf];
        char* bd = (char*)Bs[buf];
        gload16(Ag0 + k0, ad + tid * 16);
        gload16(Ag1 + k0, ad + (tid + 256) * 16);
        gload16(Bg0 + k0, bd + tid * 16);
        gload16(Bg1 + k0, bd + (tid + 256) * 16);
    };
    auto compute = [&](int buf) {
        const char* ab = (const char*)As[buf];
        const char* bb = (const char*)Bs[buf];
        short8 a[4], b[4];
#pragma unroll
        for (int t = 0; t < 4; ++t) a[t] = *reinterpret_cast<const short8*>(ab + aOff[t]);
#pragma unroll
        for (int u = 0; u < 4; ++u) b[u] = *reinterpret_cast<const short8*>(bb + bOff[u]);
#pragma unroll
        for (int t = 0; t < 4; ++t)
#pragma unroll
            for (int u = 0; u < 4; ++u)
                acc[t][u] = __builtin_amdgcn_mfma_f32_16x16x32_bf16(a[t], b[u], acc[t][u], 0, 0, 0);
    };

    const int nsteps = Kc >> 5;          // >= 16, even
    // prologue: two stages in flight (8 vm ops)
    stage(0, 0);
    stage(1, 32);
    int kst = 64;
    int t = 0;

    // Per iteration: wait step t's loads (leave step t+1 in flight), barrier
    // (all waves have buf t ready AND finished compute t-1), pin everything
    // below the barrier, stage step t+2 into buf (t+2)%3, compute step t.
#define PIPE_ITER(B) { \
        if (t == nsteps - 1) { asm volatile("s_waitcnt vmcnt(0)" ::: "memory"); } \
        else                 { asm volatile("s_waitcnt vmcnt(4)" ::: "memory"); } \
        __builtin_amdgcn_s_barrier(); \
        __builtin_amdgcn_sched_barrier(0); \
        if (kst < Kc) { stage(((B) + 2) % 3, kst); kst += 32; } \
        compute(B); \
        ++t; }

    while (t + 3 <= nsteps) { PIPE_ITER(0) PIPE_ITER(1) PIPE_ITER(2) }
    if (t < nsteps) { PIPE_ITER(0) }
    if (t < nsteps) { PIPE_ITER(1) }
#undef PIPE_ITER

    // C/D layout: col = lane&15, row = quad*4 + reg   [verified m89]
    bool addb = (bias != nullptr) && (bz == 0);
#pragma unroll
    for (int t2 = 0; t2 < 4; ++t2) {
#pragma unroll
        for (int u = 0; u < 4; ++u) {
            int col = bn + wn * 64 + u * 16 + l16;
            float bcol = addb ? bias[col] : 0.0f;
#pragma unroll
            for (int i = 0; i < 4; ++i) {
                int row = bm + wm * 64 + t2 * 16 + quad * 4 + i;
                if (row >= M) continue;
                float val = acc[t2][u][i] + bcol;
                size_t idx = (size_t)row * N + col;
                if (MODE == 0) {
                    if (pos) val += pos[(size_t)(row % LTOK) * N + col];
                    Cf[idx] = val;
                } else if (MODE == 1) {
                    Cf[idx] += val;
                } else if (MODE == 2) {
                    float u3 = val * val * val;
                    float g = 0.5f * val *
                        (1.0f + tanhf(0.7978845608028654f * (val + 0.044715f * u3)));
                    Cb[idx] = __float2bfloat16(g);
                } else if (MODE == 3) {
                    Cb[idx] = __float2bfloat16(val);
                } else {                                   // MODE 4: partial slice
                    Cf[(size_t)bz * ((size_t)M * N) + idx] = val;
                }
            }
        }
    }
}

// ---------------------------------------------------------------------------
// MFMA attention: one block per (n, h); 4 waves, each owns Q-tiles qt, qt+4.
// S=99 padded to 112 (7 key tiles of 16). q/k fragments loaded directly from
// global (16B contiguous); V transposed into LDS once; P via wave-private LDS.
// ---------------------------------------------------------------------------
__global__ __launch_bounds__(256) void attn_mfma(
    const __hip_bfloat16* __restrict__ qkv, __hip_bfloat16* __restrict__ o)
{
    int n = blockIdx.x >> 4, h = blockIdx.x & 15;
    int tid = threadIdx.x, lane = tid & 63, wid = tid >> 6;
    int quad = lane >> 4, l16 = lane & 15;

    __shared__ __hip_bfloat16 Vt[DHEAD * VT_PITCH];      // [d][key] 17408 B
    __shared__ __hip_bfloat16 Ps[4][16 * P_PITCH];       // wave-private P, 17408 B

    // zero Vt (pad keys >= 99 must be 0) and Ps (pad cols 112.. must be 0)
    {
        int4 zz = make_int4(0, 0, 0, 0);
        int4* v4 = (int4*)Vt;
        int4* p4 = (int4*)Ps;
        for (int i = tid; i < (DHEAD * VT_PITCH) / 8; i += 256) v4[i] = zz;
        for (int i = tid; i < (4 * 16 * P_PITCH) / 8; i += 256) p4[i] = zz;
    }
    __syncthreads();
    // stage V transposed: Vt[d][s] = v[s][d]
    for (int idx = tid; idx < SEQ * DHEAD; idx += 256) {
        int s = idx >> 6, d = idx & 63;
        Vt[d * VT_PITCH + s] = qkv[((size_t)(n * SEQ + s)) * QS + 2 * DMODEL + h * DHEAD + d];
    }
    __syncthreads();

    const short* qbase = reinterpret_cast<const short*>(qkv) + (size_t)n * SEQ * QS + h * DHEAD;
    const short* kbase = qbase + DMODEL;
    const float scale = 0.125f;  // 1/sqrt(64)

    for (int qt = wid; qt < 7; qt += 4) {
        int q0 = qt * 16;
        // A-fragments of Q: lane m=l16 -> row q0+l16, k = c*32 + quad*8
        int qrow = q0 + l16; if (qrow >= SEQ) qrow = SEQ - 1;
        const short* qp = qbase + (size_t)qrow * QS + quad * 8;
        short8 aq0 = *reinterpret_cast<const short8*>(qp);
        short8 aq1 = *reinterpret_cast<const short8*>(qp + 32);

        // QK^T: scores sc[u] for key tile u (C-layout: row=quad*4+i, col=l16)
        f32x4 sc[7];
#pragma unroll
        for (int u = 0; u < 7; ++u) {
            int krow = u * 16 + l16; if (krow >= SEQ) krow = SEQ - 1;
            const short* kp = kbase + (size_t)krow * QS + quad * 8;
            short8 kb0 = *reinterpret_cast<const short8*>(kp);
            short8 kb1 = *reinterpret_cast<const short8*>(kp + 32);
            f32x4 s = {0.f, 0.f, 0.f, 0.f};
            s = __builtin_amdgcn_mfma_f32_16x16x32_bf16(aq0, kb0, s, 0, 0, 0);
            s = __builtin_amdgcn_mfma_f32_16x16x32_bf16(aq1, kb1, s, 0, 0, 0);
            sc[u] = s;
        }
        // scale + mask keys >= 99 (only tile u=6: keys 96..111 -> l16 >= 3)
#pragma unroll
        for (int u = 0; u < 7; ++u)
#pragma unroll
            for (int i = 0; i < 4; ++i)
                sc[u][i] *= scale;
        if (l16 >= 3) {
#pragma unroll
            for (int i = 0; i < 4; ++i) sc[6][i] = -1e30f;
        }
        // row softmax (row = quad*4+i spans 16 lanes l16 x 7 tiles)
#pragma unroll
        for (int i = 0; i < 4; ++i) {
            float m = sc[0][i];
#pragma unroll
            for (int u = 1; u < 7; ++u) m = fmaxf(m, sc[u][i]);
            m = fmaxf(m, __shfl_xor(m, 1));
            m = fmaxf(m, __shfl_xor(m, 2));
            m = fmaxf(m, __shfl_xor(m, 4));
            m = fmaxf(m, __shfl_xor(m, 8));
            float sum = 0.f;
#pragma unroll
            for (int u = 0; u < 7; ++u) {
                float e = __expf(sc[u][i] - m);
                sc[u][i] = e;
                sum += e;
            }
            sum += __shfl_xor(sum, 1);
            sum += __shfl_xor(sum, 2);
            sum += __shfl_xor(sum, 4);
            sum += __shfl_xor(sum, 8);
            float inv = 1.0f / sum;
            // write P row (C-layout -> LDS), cols 112..135 stay zero
            __hip_bfloat16* pr = &Ps[wid][(quad * 4 + i) * P_PITCH];
#pragma unroll
            for (int u = 0; u < 7; ++u)
                pr[u * 16 + l16] = __float2bfloat16(sc[u][i] * inv);
        }
        // PV: A = P (A-layout: lane m=l16 -> row l16, k = kc*32+quad*8)
        short8 ap[4];
#pragma unroll
        for (int kc = 0; kc < 4; ++kc)
            ap[kc] = *reinterpret_cast<const short8*>(&Ps[wid][l16 * P_PITCH + kc * 32 + quad * 8]);
        f32x4 oacc[4];
#pragma unroll
        for (int dt = 0; dt < 4; ++dt) { f32x4 z = {0.f, 0.f, 0.f, 0.f}; oacc[dt] = z; }
#pragma unroll
        for (int kc = 0; kc < 4; ++kc) {
#pragma unroll
            for (int dt = 0; dt < 4; ++dt) {
                short8 vb = *reinterpret_cast<const short8*>(
                    &Vt[(dt * 16 + l16) * VT_PITCH + kc * 32 + quad * 8]);
                oacc[dt] = __builtin_amdgcn_mfma_f32_16x16x32_bf16(ap[kc], vb, oacc[dt], 0, 0, 0);
            }
        }
        // store O (C-layout): row q0+quad*4+i, col = h*64 + dt*16+l16
#pragma unroll
        for (int dt = 0; dt < 4; ++dt) {
#pragma unroll
            for (int i = 0; i < 4; ++i) {
                int row = q0 + quad * 4 + i;
                if (row < SEQ)
                    o[((size_t)(n * SEQ + row)) * DMODEL + h * DHEAD + dt * 16 + l16] =
                        __float2bfloat16(oacc[dt][i]);
            }
        }
    }
}

// ---------------------------------------------------------------------------
extern "C" void kernel_launch(void* const* d_in, const int* in_sizes, int n_in,
                              void* d_out, int out_size, void* d_ws, size_t ws_size,
                              hipStream_t stream)
{
    (void)in_sizes; (void)n_in; (void)out_size;
    const float* imgs    = (const float*)d_in[0];
    const float* noise   = (const float*)d_in[1];
    const float* patch_w = (const float*)d_in[2];
    const float* patch_b = (const float*)d_in[3];
    const float* pos_emb = (const float*)d_in[4];
    const float* cls     = (const float*)d_in[5];
    const float* ln1_s   = (const float*)d_in[6];
    const float* ln1_b   = (const float*)d_in[7];
    const float* wq      = (const float*)d_in[8];
    const float* bq      = (const float*)d_in[9];
    const float* wk      = (const float*)d_in[10];
    const float* bk      = (const float*)d_in[11];
    const float* wv      = (const float*)d_in[12];
    const float* bv      = (const float*)d_in[13];
    const float* wo      = (const float*)d_in[14];
    const float* bo      = (const float*)d_in[15];
    const float* ln2_s   = (const float*)d_in[16];
    const float* ln2_b   = (const float*)d_in[17];
    const float* w1      = (const float*)d_in[18];
    const float* b1      = (const float*)d_in[19];
    const float* w2      = (const float*)d_in[20];
    const float* b2      = (const float*)d_in[21];
    const float* lnf_s   = (const float*)d_in[22];
    const float* lnf_b   = (const float*)d_in[23];

    float* out_x    = (float*)d_out;
    float* out_mask = out_x + (size_t)NS * DMODEL;

    // ---- workspace carve-up ----
    char* p = (char*)d_ws;
    auto alloc = [&](size_t bytes) {
        char* r = p; p += (bytes + 255) & ~(size_t)255; return r;
    };
    __hip_bfloat16* patch_wt = (__hip_bfloat16*)alloc((size_t)DMODEL * PDIM * 2);
    __hip_bfloat16* wqkvt    = (__hip_bfloat16*)alloc((size_t)NLAYERS * QS * DMODEL * 2);
    __hip_bfloat16* wot = (__hip_bfloat16*)alloc((size_t)NLAYERS * DMODEL * DMODEL * 2);
    __hip_bfloat16* w1t = (__hip_bfloat16*)alloc((size_t)NLAYERS * DMODEL * DMLP * 2);
    __hip_bfloat16* w2t = (__hip_bfloat16*)alloc((size_t)NLAYERS * DMODEL * DMLP * 2);
    float* bqkv     = (float*)alloc((size_t)NLAYERS * QS * 4);
    int*   ids_keep = (int*)alloc((size_t)NIMG * NKEEP * 4);
    float* x        = (float*)alloc((size_t)NS * DMODEL * 4);
    // scratch region: layer buffers, aliased with pre-layer Apatch/x0
    char* scratch = p;
    __hip_bfloat16* ybf  = (__hip_bfloat16*)alloc((size_t)NS * DMODEL * 2);
    __hip_bfloat16* qkv  = (__hip_bfloat16*)alloc((size_t)NS * QS * 2);
    __hip_bfloat16* obf  = (__hip_bfloat16*)alloc((size_t)NS * DMODEL * 2);
    __hip_bfloat16* h1bf = (__hip_bfloat16*)alloc((size_t)NS * DMLP * 2);
    // aliases (dead once gather_cls has run):
    __hip_bfloat16* Apatch = (__hip_bfloat16*)scratch;                       // NP*PDIM bf16
    float* x0 = (float*)(scratch + (((size_t)NP * PDIM * 2 + 255) & ~(size_t)255)); // NP*D f32
    // split-K partial slices carved LAST; only used if workspace allows
    float* partial = (float*)alloc((size_t)2 * NS * DMODEL * 4);
    bool useSK = (size_t)(p - (char*)d_ws) <= ws_size;

    const size_t DD = (size_t)DMODEL * DMODEL;
    const size_t DM = (size_t)DMODEL * DMLP;

    // ---- weight conversion (every call; ws is re-poisoned) ----
    conv_transpose<<<dim3(DMODEL / 32, PDIM / 32, 1), 256, 0, stream>>>(
        patch_w, patch_wt, PDIM, DMODEL, PDIM * DMODEL, PDIM * DMODEL);
    conv_transpose<<<dim3(DMODEL / 32, DMODEL / 32, NLAYERS), 256, 0, stream>>>(
        wq, wqkvt, DMODEL, DMODEL, DD, (size_t)QS * DMODEL);
    conv_transpose<<<dim3(DMODEL / 32, DMODEL / 32, NLAYERS), 256, 0, stream>>>(
        wk, wqkvt + DD, DMODEL, DMODEL, DD, (size_t)QS * DMODEL);
    conv_transpose<<<dim3(DMODEL / 32, DMODEL / 32, NLAYERS), 256, 0, stream>>>(
        wv, wqkvt + 2 * DD, DMODEL, DMODEL, DD, (size_t)QS * DMODEL);
    conv_transpose<<<dim3(DMODEL / 32, DMODEL / 32, NLAYERS), 256, 0, stream>>>(
        wo, wot, DMODEL, DMODEL, DD, DD);
    conv_transpose<<<dim3(DMLP / 32, DMODEL / 32, NLAYERS), 256, 0, stream>>>(
        w1, w1t, DMODEL, DMLP, DM, DM);
    conv_transpose<<<dim3(DMODEL / 32, DMLP / 32, NLAYERS), 256, 0, stream>>>(
        w2, w2t, DMLP, DMODEL, DM, DM);
    concat_bias<<<dim3(QS / 256, NLAYERS), 256, 0, stream>>>(bq, bk, bv, bqkv);

    // ---- masking / patch embed ----
    sort_kernel<<<NIMG, 256, 0, stream>>>(noise, ids_keep, out_mask);
    patchify<<<NP, 256, 0, stream>>>(imgs, Apatch);
    gemm_mfma<0><<<dim3(NP / 128, DMODEL / 128), 256, 0, stream>>>(
        Apatch, patch_wt, patch_b, pos_emb, x0, nullptr, NP, DMODEL, PDIM);
    gather_cls<<<NS, 256, 0, stream>>>(x0, cls, ids_keep, x);

    // ---- transformer layers ----
    dim3 gQKV((NS + 127) / 128, QS / 128);
    dim3 gD((NS + 127) / 128, DMODEL / 128);
    dim3 gM((NS + 127) / 128, DMLP / 128);
    dim3 gSK((NS + 127) / 128, DMODEL / 128, 2);   // split-K=2, partial slices
    for (int L = 0; L < NLAYERS; ++L) {
        size_t wDD = (size_t)L * DD;
        size_t wDM = (size_t)L * DM;
        if (L == 0 || !useSK)
            ln_kernel<1, 0><<<NS, 256, 0, stream>>>(x, nullptr, nullptr, nullptr,
                ln1_s + L * DMODEL, ln1_b + L * DMODEL, nullptr, ybf);
        else
            ln_kernel<1, 2><<<NS, 256, 0, stream>>>(x, x, partial, b2 + (size_t)(L - 1) * DMODEL,
                ln1_s + L * DMODEL, ln1_b + L * DMODEL, nullptr, ybf);
        gemm_mfma<3><<<gQKV, 256, 0, stream>>>(ybf, wqkvt + (size_t)L * QS * DMODEL,
                                               bqkv + (size_t)L * QS, nullptr, nullptr, qkv,
                                               NS, QS, DMODEL);
        attn_mfma<<<NIMG * NHEADS, 256, 0, stream>>>(qkv, obf);
        if (useSK) {
            gemm_mfma<4><<<gSK, 256, 0, stream>>>(obf, wot + wDD, nullptr, nullptr,
                                                  partial, nullptr, NS, DMODEL, DMODEL);
            ln_kernel<1, 2><<<NS, 256, 0, stream>>>(x, x, partial, bo + (size_t)L * DMODEL,
                ln2_s + L * DMODEL, ln2_b + L * DMODEL, nullptr, ybf);
        } else {
            gemm_mfma<1><<<gD, 256, 0, stream>>>(obf, wot + wDD, bo + L * DMODEL, nullptr,
                                                 x, nullptr, NS, DMODEL, DMODEL);
            ln_kernel<1, 0><<<NS, 256, 0, stream>>>(x, nullptr, nullptr, nullptr,
                ln2_s + L * DMODEL, ln2_b + L * DMODEL, nullptr, ybf);
        }
        gemm_mfma<2><<<gM, 256, 0, stream>>>(ybf, w1t + wDM, b1 + L * DMLP, nullptr,
                                             nullptr, h1bf, NS, DMLP, DMODEL);
        if (useSK) {
            gemm_mfma<4><<<gSK, 256, 0, stream>>>(h1bf, w2t + wDM, nullptr, nullptr,
                                                  partial, nullptr, NS, DMODEL, DMLP);
        } else {
            gemm_mfma<1><<<gD, 256, 0, stream>>>(h1bf, w2t + wDM, b2 + L * DMODEL, nullptr,
                                                 x, nullptr, NS, DMODEL, DMLP);
        }
    }

    // ---- final LN -> output ----
    if (useSK)
        ln_kernel<0, 2><<<NS, 256, 0, stream>>>(x, x, partial, b2 + (size_t)5 * DMODEL,
                                                lnf_s, lnf_b, out_x, nullptr);
    else
        ln_kernel<0, 0><<<NS, 256, 0, stream>>>(x, nullptr, nullptr, nullptr,
                                                lnf_s, lnf_b, out_x, nullptr);
}